// Round 1
// 594.110 us; speedup vs baseline: 1.2223x; 1.2223x over previous
//
#include <hip/hip_runtime.h>
#include <hip/hip_bf16.h>

using bf16 = __hip_bfloat16;

#define B_  64
#define C_  256
#define HD_ 256
#define XS  31
#define XO  29
#define ZS  7
#define ZO  5
#define OSP 25
#define XO2 (XO*XO)    // 841
#define ZO2 (ZO*ZO)    // 25
#define OS2 (OSP*OSP)  // 625
#define EPSF 1e-5f

typedef __attribute__((ext_vector_type(4))) float f32x4;
typedef __attribute__((ext_vector_type(8))) short s16x8;

__device__ __forceinline__ unsigned short f2bf(float f) {
    union { float f; unsigned int u; } a; a.f = f;
    unsigned int r = a.u + 0x7FFF + ((a.u >> 16) & 1);   // RNE
    return (unsigned short)(r >> 16);
}
__device__ __forceinline__ unsigned int pk2(unsigned short a, unsigned short b) {
    return (unsigned int)a | ((unsigned int)b << 16);
}

// ---------------------------------------------------------------------------
// One-time fp32->bf16 conversion of all GEMM weights into workspace.
// Layout: [head_w 3*65536 | cls_w1 3*65536 | loc_w1 3*65536 | ctr_w1 3*65536]
// ---------------------------------------------------------------------------
__global__ void wconv_k(const float* __restrict__ hw, const float* __restrict__ cw,
                        const float* __restrict__ lw, const float* __restrict__ tw,
                        unsigned short* __restrict__ o)
{
    int i = blockIdx.x * 256 + threadIdx.x;
    if (i >= 4 * 196608) return;
    int seg = i / 196608, r = i - seg * 196608;
    const float* s = (seg == 0) ? hw : (seg == 1) ? cw : (seg == 2) ? lw : tw;
    o[i] = f2bf(s[r]);
}

// ---------------------------------------------------------------------------
// Fused: dw3+BN+ReLU on x-tile and z-tile, then depthwise 5x5 xcorr.
// One block per (b,c); blockIdx.y = local stage (batched) else 0.
// v3: LDS strides padded 32->33 (xt) / 32->36 (st): old layout had bank =
//   f(c0 only) -> 8-way conflicts on every dw3/xcorr read; now ~2-way (free).
// ---------------------------------------------------------------------------
__global__ __launch_bounds__(256) void fused_pre_xcorr(
    const float* __restrict__ x, const float* __restrict__ z,
    const float* __restrict__ w, const float* __restrict__ g,
    const float* __restrict__ bb, const float* __restrict__ mm,
    const float* __restrict__ vv, unsigned short* __restrict__ out,
    int si_base)
{
    const int zs  = blockIdx.y;            // local stage index (output buffer)
    const int si  = si_base + zs;          // global stage index (inputs)
    const int bc  = blockIdx.x;
    const int c   = bc & (C_ - 1);
    const int tid = threadIdx.x;

    __shared__ float xt[31 * 33 + 16];   // x tile, row stride 33 (bank spread)
    __shared__ float st[29 * 36 + 8];    // search feature, row stride 36 (16B-aligned float4)
    __shared__ float zt[49];
    __shared__ float ktl[25];
    __shared__ float wtl[9];

    const float* xp = x + ((size_t)si * B_ * C_ + bc) * (XS * XS);
    for (int j = tid; j < XS * XS; j += 256) xt[(j / 31) * 33 + (j % 31)] = xp[j];
    if (tid < 49) zt[tid] = z[((size_t)si * B_ * C_ + bc) * 49 + tid];
    if (tid < 9)  wtl[tid] = w[((size_t)si * C_ + c) * 9 + tid];
    const int cg = si * C_ + c;
    const float inv  = g[cg] * rsqrtf(vv[cg] + EPSF);
    const float beta = bb[cg] - mm[cg] * inv;
    __syncthreads();

    float wr[9];
    #pragma unroll
    for (int j = 0; j < 9; ++j) wr[j] = wtl[j];

    // kernel features (5x5), threads 0..24
    if (tid < 25) {
        int oy = tid / 5, ox = tid - (tid / 5) * 5;
        float a = 0.f;
        #pragma unroll
        for (int dy = 0; dy < 3; ++dy)
            #pragma unroll
            for (int dx = 0; dx < 3; ++dx)
                a += zt[(oy + dy) * ZS + ox + dx] * wr[dy * 3 + dx];
        ktl[tid] = fmaxf(a * inv + beta, 0.f);
    }

    // search features: 29 rows x 8 col-groups of 4; threads 0..231
    if (tid < 232) {
        int r = tid >> 3, c0 = (tid & 7) * 4;
        float o0 = 0.f, o1 = 0.f, o2 = 0.f, o3 = 0.f;
        #pragma unroll
        for (int dy = 0; dy < 3; ++dy) {
            const float* row = &xt[(r + dy) * 33 + c0];
            float v0 = row[0], v1 = row[1], v2 = row[2],
                  v3 = row[3], v4 = row[4], v5 = row[5];
            float w0 = wr[dy * 3], w1 = wr[dy * 3 + 1], w2 = wr[dy * 3 + 2];
            o0 += v0 * w0 + v1 * w1 + v2 * w2;
            o1 += v1 * w0 + v2 * w1 + v3 * w2;
            o2 += v2 * w0 + v3 * w1 + v4 * w2;
            o3 += v3 * w0 + v4 * w1 + v5 * w2;
        }
        float4 res;
        res.x = fmaxf(o0 * inv + beta, 0.f);
        res.y = fmaxf(o1 * inv + beta, 0.f);
        res.z = fmaxf(o2 * inv + beta, 0.f);
        res.w = fmaxf(o3 * inv + beta, 0.f);
        *(float4*)&st[r * 36 + c0] = res;   // cols >=29 land in pad, never read
    }
    __syncthreads();

    // xcorr: threads 0..124, each computes 5 consecutive outputs of one row
    if (tid < 125) {
        float kt[25];
        #pragma unroll
        for (int j = 0; j < 25; ++j) kt[j] = ktl[j];
        int u = tid / 5, v0 = (tid - (tid / 5) * 5) * 5;
        float o0 = 0.f, o1 = 0.f, o2 = 0.f, o3 = 0.f, o4 = 0.f;
        #pragma unroll
        for (int p = 0; p < 5; ++p) {
            const float* row = &st[(u + p) * 36 + v0];
            float r0 = row[0], r1 = row[1], r2 = row[2], r3 = row[3], r4 = row[4],
                  r5 = row[5], r6 = row[6], r7 = row[7], r8 = row[8];
            float k0 = kt[p * 5], k1 = kt[p * 5 + 1], k2 = kt[p * 5 + 2],
                  k3 = kt[p * 5 + 3], k4 = kt[p * 5 + 4];
            o0 += r0 * k0 + r1 * k1 + r2 * k2 + r3 * k3 + r4 * k4;
            o1 += r1 * k0 + r2 * k1 + r3 * k2 + r4 * k3 + r5 * k4;
            o2 += r2 * k0 + r3 * k1 + r4 * k2 + r5 * k3 + r6 * k4;
            o3 += r3 * k0 + r4 * k1 + r5 * k2 + r6 * k3 + r7 * k4;
            o4 += r4 * k0 + r5 * k1 + r6 * k2 + r7 * k3 + r8 * k4;
        }
        unsigned short* op = out + ((size_t)zs * B_ * C_ + bc) * OS2 + u * OSP + v0;
        op[0] = f2bf(o0); op[1] = f2bf(o1); op[2] = f2bf(o2);
        op[3] = f2bf(o3); op[4] = f2bf(o4);
    }
}

// ---------------------------------------------------------------------------
// Head GEMM: feat[b][o][s] = relu(bn(sum_c W[o][c] * X[b][c][s])), bf16 out.
// Block tile 128x128, K-chunks of 32, 4 waves, 16x16x32 MFMA.
// grid (5, 2, nstage*64). Wbf (bf16 weights) when non-null skips per-block
// fp32->bf16 conversion (was ~80 VALU ops/thread/K-step, redundant per block).
// ---------------------------------------------------------------------------
__global__ __launch_bounds__(256) void c1_mfma(
    const unsigned short* __restrict__ X,
    const float* __restrict__ W,
    const unsigned short* __restrict__ Wbf,
    const float* __restrict__ g, const float* __restrict__ bb,
    const float* __restrict__ mm, const float* __restrict__ vv,
    unsigned short* __restrict__ out, int si_base)
{
    __shared__ unsigned short Abuf[4 * 128 * 8];
    __shared__ unsigned short Bbuf[4 * 128 * 8];
    __shared__ float s_inv[128], s_beta[128];

    const int tid  = threadIdx.x;
    const int wave = tid >> 6, lane = tid & 63;
    const int quad = lane >> 4, l16 = lane & 15;
    const int sb = blockIdx.x * 128;
    const int ob = blockIdx.y * 128;
    const int zs = blockIdx.z >> 6;
    const int si = si_base + zs;
    const int b  = blockIdx.z & 63;
    const int wm = (wave & 1) * 64, wn = (wave >> 1) * 64;

    const float* gs  = g  + (size_t)si * HD_;
    const float* bbs = bb + (size_t)si * HD_;
    const float* mms = mm + (size_t)si * HD_;
    const float* vvs = vv + (size_t)si * HD_;
    const float* Ws  = W  + (size_t)si * HD_ * C_;
    const unsigned short* Wbs = Wbf ? Wbf + (size_t)si * HD_ * C_ : nullptr;

    if (tid < 128) {
        int o = ob + tid;
        float iv = gs[o] * rsqrtf(vvs[o] + EPSF);
        s_inv[tid]  = iv;
        s_beta[tid] = bbs[o] - mms[o] * iv;
    }

    const int sm = tid & 127;
    const int kh = tid >> 7;
    const unsigned short* Xb = X + ((size_t)zs * B_ + b) * C_ * OS2;
    const bool npred = (sb + sm) < OS2;

    f32x4 acc[4][4];
    #pragma unroll
    for (int i = 0; i < 4; ++i)
        #pragma unroll
        for (int j = 0; j < 4; ++j)
            acc[i][j] = (f32x4){0.f, 0.f, 0.f, 0.f};

    for (int kk = 0; kk < C_; kk += 32) {
        uint4 pa0, pa1;
        if (Wbs) {
            const unsigned short* wp = Wbs + (size_t)(ob + sm) * C_ + kk + kh * 16;
            pa0 = *(const uint4*)(wp);
            pa1 = *(const uint4*)(wp + 8);
        } else {
            const float* wp = Ws + (size_t)(ob + sm) * C_ + kk + kh * 16;
            float4 w0 = *(const float4*)(wp + 0);
            float4 w1 = *(const float4*)(wp + 4);
            float4 w2 = *(const float4*)(wp + 8);
            float4 w3 = *(const float4*)(wp + 12);
            pa0.x = pk2(f2bf(w0.x), f2bf(w0.y)); pa0.y = pk2(f2bf(w0.z), f2bf(w0.w));
            pa0.z = pk2(f2bf(w1.x), f2bf(w1.y)); pa0.w = pk2(f2bf(w1.z), f2bf(w1.w));
            pa1.x = pk2(f2bf(w2.x), f2bf(w2.y)); pa1.y = pk2(f2bf(w2.z), f2bf(w2.w));
            pa1.z = pk2(f2bf(w3.x), f2bf(w3.y)); pa1.w = pk2(f2bf(w3.z), f2bf(w3.w));
        }
        *(uint4*)&Abuf[((kh * 2 + 0) * 128 + sm) * 8] = pa0;
        *(uint4*)&Abuf[((kh * 2 + 1) * 128 + sm) * 8] = pa1;

        unsigned short bu[16];
        #pragma unroll
        for (int j = 0; j < 16; ++j)
            bu[j] = npred ? Xb[(size_t)(kk + kh * 16 + j) * OS2 + sb + sm]
                          : (unsigned short)0;
        uint4 pb0, pb1;
        pb0.x = pk2(bu[0],  bu[1]);  pb0.y = pk2(bu[2],  bu[3]);
        pb0.z = pk2(bu[4],  bu[5]);  pb0.w = pk2(bu[6],  bu[7]);
        pb1.x = pk2(bu[8],  bu[9]);  pb1.y = pk2(bu[10], bu[11]);
        pb1.z = pk2(bu[12], bu[13]); pb1.w = pk2(bu[14], bu[15]);
        *(uint4*)&Bbuf[((kh * 2 + 0) * 128 + sm) * 8] = pb0;
        *(uint4*)&Bbuf[((kh * 2 + 1) * 128 + sm) * 8] = pb1;

        __syncthreads();

        s16x8 af[4], bfr[4];
        #pragma unroll
        for (int mt = 0; mt < 4; ++mt)
            af[mt] = *(const s16x8*)&Abuf[(quad * 128 + wm + mt * 16 + l16) * 8];
        #pragma unroll
        for (int nt = 0; nt < 4; ++nt)
            bfr[nt] = *(const s16x8*)&Bbuf[(quad * 128 + wn + nt * 16 + l16) * 8];
        #pragma unroll
        for (int mt = 0; mt < 4; ++mt)
            #pragma unroll
            for (int nt = 0; nt < 4; ++nt)
                acc[mt][nt] = __builtin_amdgcn_mfma_f32_16x16x32_bf16(
                    af[mt], bfr[nt], acc[mt][nt], 0, 0, 0);

        __syncthreads();
    }

    #pragma unroll
    for (int mt = 0; mt < 4; ++mt) {
        #pragma unroll
        for (int r = 0; r < 4; ++r) {
            int orow = wm + mt * 16 + quad * 4 + r;
            float iv = s_inv[orow], be = s_beta[orow];
            size_t obase = (((size_t)zs * B_ + b) * HD_ + (ob + orow)) * OS2;
            #pragma unroll
            for (int nt = 0; nt < 4; ++nt) {
                int s = sb + wn + nt * 16 + l16;
                if (s < OS2)
                    out[obase + s] = f2bf(fmaxf(acc[mt][nt][r] * iv + be, 0.f));
            }
        }
    }
}

// ---------------------------------------------------------------------------
// Fused 3-head hidden GEMM + w2 projection + softmax-weighted accumulate.
// grid (5 s-tiles, 6 o-tiles [cls,cls,loc,loc,ctr,ctr], nstage*64 b).
// ---------------------------------------------------------------------------
__global__ __launch_bounds__(256) void heads3_mfma(
    const unsigned short* __restrict__ feat,
    const float* __restrict__ w1c, const float* __restrict__ w1l, const float* __restrict__ w1t,
    const unsigned short* __restrict__ Wbf,
    const float* __restrict__ gc, const float* __restrict__ bc2, const float* __restrict__ mc, const float* __restrict__ vc,
    const float* __restrict__ gl, const float* __restrict__ bl, const float* __restrict__ ml, const float* __restrict__ vl,
    const float* __restrict__ gt, const float* __restrict__ bt, const float* __restrict__ mt2, const float* __restrict__ vt,
    const float* __restrict__ w2c, const float* __restrict__ w2l, const float* __restrict__ w2t,
    const float* __restrict__ wvc, const float* __restrict__ wvl, const float* __restrict__ wvt,
    int si_base, float* __restrict__ oacc)
{
    __shared__ unsigned short Abuf[4 * 128 * 8];
    __shared__ unsigned short Bbuf[4 * 128 * 8];
    __shared__ float s_inv[128], s_beta[128];
    __shared__ float s_w2[4 * 256];

    const int tid  = threadIdx.x;
    const int wave = tid >> 6, lane = tid & 63;
    const int quad = lane >> 4, l16 = lane & 15;
    const int sb   = blockIdx.x * 128;
    const int by   = blockIdx.y;
    const int head = by >> 1;
    const int lob  = (by & 1) * 128;
    const int zs   = blockIdx.z >> 6;
    const int si   = si_base + zs;
    const int b    = blockIdx.z & 63;
    const int wm = (wave & 1) * 64, wn = (wave >> 1) * 64;

    const float* W  = (head == 0) ? w1c : (head == 1) ? w1l : w1t;
    const float* g  = (head == 0) ? gc  : (head == 1) ? gl  : gt;
    const float* bb = (head == 0) ? bc2 : (head == 1) ? bl  : bt;
    const float* mm = (head == 0) ? mc  : (head == 1) ? ml  : mt2;
    const float* vv = (head == 0) ? vc  : (head == 1) ? vl  : vt;
    const float* w2 = (head == 0) ? w2c : (head == 1) ? w2l : w2t;
    const float* wv = (head == 0) ? wvc : (head == 1) ? wvl : wvt;
    const int  CON  = (head == 0) ? 2 : (head == 1) ? 4 : 1;

    const float* Ws  = W + (size_t)si * HD_ * C_;
    const unsigned short* Wbs =
        Wbf ? Wbf + (size_t)(head + 1) * (3 * HD_ * C_) + (size_t)si * HD_ * C_ : nullptr;
    g  += (size_t)si * HD_;  bb += (size_t)si * HD_;
    mm += (size_t)si * HD_;  vv += (size_t)si * HD_;
    w2 += (size_t)si * CON * HD_;

    if (tid < 128) {
        int o = lob + tid;
        float iv = g[o] * rsqrtf(vv[o] + EPSF);
        s_inv[tid]  = iv;
        s_beta[tid] = bb[o] - mm[o] * iv;
    }
    for (int t = tid; t < CON * 256; t += 256) s_w2[t] = w2[t];

    const int sm = tid & 127;
    const int kh = tid >> 7;
    const unsigned short* Xb = feat + ((size_t)zs * B_ + b) * C_ * OS2;
    const bool npred = (sb + sm) < OS2;

    f32x4 acc[4][4];
    #pragma unroll
    for (int i = 0; i < 4; ++i)
        #pragma unroll
        for (int j = 0; j < 4; ++j)
            acc[i][j] = (f32x4){0.f, 0.f, 0.f, 0.f};

    for (int kk = 0; kk < C_; kk += 32) {
        uint4 pa0, pa1;
        if (Wbs) {
            const unsigned short* wp = Wbs + (size_t)(lob + sm) * C_ + kk + kh * 16;
            pa0 = *(const uint4*)(wp);
            pa1 = *(const uint4*)(wp + 8);
        } else {
            const float* wp = Ws + (size_t)(lob + sm) * C_ + kk + kh * 16;
            float4 w0 = *(const float4*)(wp + 0);
            float4 w1 = *(const float4*)(wp + 4);
            float4 w2v4 = *(const float4*)(wp + 8);
            float4 w3 = *(const float4*)(wp + 12);
            pa0.x = pk2(f2bf(w0.x), f2bf(w0.y)); pa0.y = pk2(f2bf(w0.z), f2bf(w0.w));
            pa0.z = pk2(f2bf(w1.x), f2bf(w1.y)); pa0.w = pk2(f2bf(w1.z), f2bf(w1.w));
            pa1.x = pk2(f2bf(w2v4.x), f2bf(w2v4.y)); pa1.y = pk2(f2bf(w2v4.z), f2bf(w2v4.w));
            pa1.z = pk2(f2bf(w3.x), f2bf(w3.y)); pa1.w = pk2(f2bf(w3.z), f2bf(w3.w));
        }
        *(uint4*)&Abuf[((kh * 2 + 0) * 128 + sm) * 8] = pa0;
        *(uint4*)&Abuf[((kh * 2 + 1) * 128 + sm) * 8] = pa1;

        unsigned short bu[16];
        #pragma unroll
        for (int j = 0; j < 16; ++j)
            bu[j] = npred ? Xb[(size_t)(kk + kh * 16 + j) * OS2 + sb + sm]
                          : (unsigned short)0;
        uint4 pb0, pb1;
        pb0.x = pk2(bu[0],  bu[1]);  pb0.y = pk2(bu[2],  bu[3]);
        pb0.z = pk2(bu[4],  bu[5]);  pb0.w = pk2(bu[6],  bu[7]);
        pb1.x = pk2(bu[8],  bu[9]);  pb1.y = pk2(bu[10], bu[11]);
        pb1.z = pk2(bu[12], bu[13]); pb1.w = pk2(bu[14], bu[15]);
        *(uint4*)&Bbuf[((kh * 2 + 0) * 128 + sm) * 8] = pb0;
        *(uint4*)&Bbuf[((kh * 2 + 1) * 128 + sm) * 8] = pb1;

        __syncthreads();

        s16x8 af[4], bfr[4];
        #pragma unroll
        for (int mt = 0; mt < 4; ++mt)
            af[mt] = *(const s16x8*)&Abuf[(quad * 128 + wm + mt * 16 + l16) * 8];
        #pragma unroll
        for (int nt = 0; nt < 4; ++nt)
            bfr[nt] = *(const s16x8*)&Bbuf[(quad * 128 + wn + nt * 16 + l16) * 8];
        #pragma unroll
        for (int mt = 0; mt < 4; ++mt)
            #pragma unroll
            for (int nt = 0; nt < 4; ++nt)
                acc[mt][nt] = __builtin_amdgcn_mfma_f32_16x16x32_bf16(
                    af[mt], bfr[nt], acc[mt][nt], 0, 0, 0);

        __syncthreads();
    }

    // BN+ReLU in place
    #pragma unroll
    for (int mt = 0; mt < 4; ++mt)
        #pragma unroll
        for (int r = 0; r < 4; ++r) {
            int orow = wm + mt * 16 + quad * 4 + r;
            float iv = s_inv[orow], be = s_beta[orow];
            #pragma unroll
            for (int nt = 0; nt < 4; ++nt)
                acc[mt][nt][r] = fmaxf(acc[mt][nt][r] * iv + be, 0.f);
        }

    const float e0 = __expf(wv[0]), e1 = __expf(wv[1]), e2 = __expf(wv[2]);
    const float wi = ((si == 0) ? e0 : (si == 1) ? e1 : e2) / (e0 + e1 + e2);

    float* obase;
    if (head == 0)      obase = oacc + (size_t)b * 2 * OS2;
    else if (head == 1) obase = oacc + (size_t)B_ * 2 * OS2 + (size_t)b * 4 * OS2;
    else                obase = oacc + (size_t)B_ * 6 * OS2 + (size_t)b * OS2;

    for (int co = 0; co < CON; ++co) {
        float red[4] = {0.f, 0.f, 0.f, 0.f};
        #pragma unroll
        for (int mt = 0; mt < 4; ++mt)
            #pragma unroll
            for (int r = 0; r < 4; ++r) {
                float w2v = s_w2[co * 256 + lob + wm + mt * 16 + quad * 4 + r];
                #pragma unroll
                for (int nt = 0; nt < 4; ++nt)
                    red[nt] += w2v * acc[mt][nt][r];
            }
        #pragma unroll
        for (int nt = 0; nt < 4; ++nt) {
            red[nt] += __shfl_xor(red[nt], 16);
            red[nt] += __shfl_xor(red[nt], 32);
        }
        if (quad == 0) {
            #pragma unroll
            for (int nt = 0; nt < 4; ++nt) {
                int s = sb + wn + nt * 16 + l16;
                if (s < OS2)
                    atomicAdd(obase + (size_t)co * OS2 + s, wi * red[nt]);
            }
        }
    }
}

// ---------------------------------------------------------------------------
// Final bias add: out += sum_i softmax(w)[i] * b2[i][co], in place on d_out.
// ---------------------------------------------------------------------------
__global__ void bias_out(float* __restrict__ out,
    const float* __restrict__ cb2, const float* __restrict__ lb2,
    const float* __restrict__ tb2, const float* __restrict__ wvc,
    const float* __restrict__ wvl, const float* __restrict__ wvt)
{
    int n = blockIdx.x * 256 + threadIdx.x;
    if (n >= B_ * 7 * OS2) return;
    float bias;
    if (n < B_ * 2 * OS2) {
        float e0 = __expf(wvc[0]), e1 = __expf(wvc[1]), e2 = __expf(wvc[2]);
        int co = (n / OS2) & 1;
        bias = (e0 * cb2[co] + e1 * cb2[2 + co] + e2 * cb2[4 + co]) / (e0 + e1 + e2);
    } else if (n < B_ * 6 * OS2) {
        float e0 = __expf(wvl[0]), e1 = __expf(wvl[1]), e2 = __expf(wvl[2]);
        int co = ((n - B_ * 2 * OS2) / OS2) & 3;
        bias = (e0 * lb2[co] + e1 * lb2[4 + co] + e2 * lb2[8 + co]) / (e0 + e1 + e2);
    } else {
        float e0 = __expf(wvt[0]), e1 = __expf(wvt[1]), e2 = __expf(wvt[2]);
        bias = (e0 * tb2[0] + e1 * tb2[1] + e2 * tb2[2]) / (e0 + e1 + e2);
    }
    out[n] += bias;
}

__global__ void fillf_k(float* __restrict__ out, int n, float v)
{
    int i = blockIdx.x * 256 + threadIdx.x;
    if (i < n) out[i] = v;
}

// ===========================================================================
extern "C" void kernel_launch(void* const* d_in, const int* in_sizes, int n_in,
                              void* d_out, int out_size, void* d_ws, size_t ws_size,
                              hipStream_t stream)
{
    static const int EXP_SIZES[36] = {
        2408448, 47235072, 6912,
        768, 768, 768, 768,
        196608, 768, 768, 768, 768,
        196608, 768, 768, 768, 768, 1536, 6,
        196608, 768, 768, 768, 768, 3072, 12,
        196608, 768, 768, 768, 768, 768, 3,
        3, 3, 3
    };
    int bad = -1;
    if (n_in != 36) bad = 99;
    else {
        for (int i = 0; i < 36; ++i)
            if (in_sizes[i] != EXP_SIZES[i]) { bad = i; break; }
    }
    if (bad < 0 && ws_size < (size_t)40960000) bad = 90;
    if (bad < 0 && out_size != 280000) bad = 95;
    if (bad >= 0) {
        fillf_k<<<(out_size + 255) / 256, 256, 0, stream>>>(
            (float*)d_out, out_size, 500.f + 4.f * bad);
        return;
    }

    const float* z_fs   = (const float*)d_in[0];
    const float* x_fs   = (const float*)d_in[1];
    const float* pre_w  = (const float*)d_in[2];
    const float* pre_g  = (const float*)d_in[3];
    const float* pre_b  = (const float*)d_in[4];
    const float* pre_m  = (const float*)d_in[5];
    const float* pre_v  = (const float*)d_in[6];
    const float* head_w = (const float*)d_in[7];
    const float* head_g = (const float*)d_in[8];
    const float* head_b = (const float*)d_in[9];
    const float* head_m = (const float*)d_in[10];
    const float* head_v = (const float*)d_in[11];
    const float* cls_w1 = (const float*)d_in[12];
    const float* cls_g  = (const float*)d_in[13];
    const float* cls_b  = (const float*)d_in[14];
    const float* cls_m  = (const float*)d_in[15];
    const float* cls_v  = (const float*)d_in[16];
    const float* cls_w2 = (const float*)d_in[17];
    const float* cls_b2 = (const float*)d_in[18];
    const float* loc_w1 = (const float*)d_in[19];
    const float* loc_g  = (const float*)d_in[20];
    const float* loc_b  = (const float*)d_in[21];
    const float* loc_m  = (const float*)d_in[22];
    const float* loc_v  = (const float*)d_in[23];
    const float* loc_w2 = (const float*)d_in[24];
    const float* loc_b2 = (const float*)d_in[25];
    const float* ctr_w1 = (const float*)d_in[26];
    const float* ctr_g  = (const float*)d_in[27];
    const float* ctr_b  = (const float*)d_in[28];
    const float* ctr_m  = (const float*)d_in[29];
    const float* ctr_v  = (const float*)d_in[30];
    const float* ctr_w2 = (const float*)d_in[31];
    const float* ctr_b2 = (const float*)d_in[32];
    const float* w_cls  = (const float*)d_in[33];
    const float* w_loc  = (const float*)d_in[34];
    const float* w_ctr  = (const float*)d_in[35];

    const int OUT_N = B_ * 7 * OS2;           // 280,000
    const size_t stageEl = (size_t)B_ * C_ * OS2;   // 10,240,000 elems (bf16)
    // batched layout: xc[3] | feat[3] | wbf (4*3*65536 bf16)
    const size_t WBF_EL = (size_t)4 * 3 * HD_ * C_; // 786,432
    const bool batched = ws_size >= (6 * stageEl + WBF_EL) * sizeof(unsigned short);

    hipMemsetAsync(d_out, 0, (size_t)OUT_N * sizeof(float), stream);

    if (batched) {
        unsigned short* xc   = (unsigned short*)d_ws;
        unsigned short* feat = xc + 3 * stageEl;
        unsigned short* wbf  = feat + 3 * stageEl;

        wconv_k<<<(4 * 196608 + 255) / 256, 256, 0, stream>>>(
            head_w, cls_w1, loc_w1, ctr_w1, wbf);

        fused_pre_xcorr<<<dim3(B_ * C_, 3), 256, 0, stream>>>(
            x_fs, z_fs, pre_w, pre_g, pre_b, pre_m, pre_v, xc, 0);

        c1_mfma<<<dim3(5, 2, 3 * B_), 256, 0, stream>>>(
            xc, head_w, wbf, head_g, head_b, head_m, head_v, feat, 0);

        heads3_mfma<<<dim3(5, 6, 3 * B_), 256, 0, stream>>>(
            feat, cls_w1, loc_w1, ctr_w1, wbf,
            cls_g, cls_b, cls_m, cls_v,
            loc_g, loc_b, loc_m, loc_v,
            ctr_g, ctr_b, ctr_m, ctr_v,
            cls_w2, loc_w2, ctr_w2,
            w_cls, w_loc, w_ctr, 0, (float*)d_out);
    } else {
        // sequential fallback: fits exactly in 40.96 MB, converts W in-kernel
        unsigned short* xc   = (unsigned short*)d_ws;
        unsigned short* feat = xc + stageEl;

        for (int i = 0; i < 3; ++i) {
            fused_pre_xcorr<<<dim3(B_ * C_, 1), 256, 0, stream>>>(
                x_fs, z_fs, pre_w, pre_g, pre_b, pre_m, pre_v, xc, i);

            c1_mfma<<<dim3(5, 2, B_), 256, 0, stream>>>(
                xc, head_w, nullptr, head_g, head_b, head_m, head_v, feat, i);

            heads3_mfma<<<dim3(5, 6, B_), 256, 0, stream>>>(
                feat, cls_w1, loc_w1, ctr_w1, nullptr,
                cls_g, cls_b, cls_m, cls_v,
                loc_g, loc_b, loc_m, loc_v,
                ctr_g, ctr_b, ctr_m, ctr_v,
                cls_w2, loc_w2, ctr_w2,
                w_cls, w_loc, w_ctr, i, (float*)d_out);
        }
    }

    bias_out<<<(OUT_N + 255) / 256, 256, 0, stream>>>(
        (float*)d_out, cls_b2, loc_b2, ctr_b2, w_cls, w_loc, w_ctr);
}

// Round 2
// 564.015 us; speedup vs baseline: 1.2875x; 1.0534x over previous
//
#include <hip/hip_runtime.h>
#include <hip/hip_bf16.h>

using bf16 = __hip_bfloat16;

#define B_  64
#define C_  256
#define HD_ 256
#define XS  31
#define XO  29
#define ZS  7
#define ZO  5
#define OSP 25
#define XO2 (XO*XO)    // 841
#define ZO2 (ZO*ZO)    // 25
#define OS2 (OSP*OSP)  // 625
#define EPSF 1e-5f

// LDS strides for fused_pre (v4)
#define XCST 976          // per-channel stride in xt (961 used, 16B-aligned)
#define SRS  36           // st row stride (floats)
#define SCST (29 * SRS)   // 1044 per-channel st stride

typedef __attribute__((ext_vector_type(4))) float f32x4;
typedef __attribute__((ext_vector_type(8))) short s16x8;

__device__ __forceinline__ unsigned short f2bf(float f) {
    union { float f; unsigned int u; } a; a.f = f;
    unsigned int r = a.u + 0x7FFF + ((a.u >> 16) & 1);   // RNE
    return (unsigned short)(r >> 16);
}
__device__ __forceinline__ unsigned int pk2(unsigned short a, unsigned short b) {
    return (unsigned int)a | ((unsigned int)b << 16);
}

// ---------------------------------------------------------------------------
// One-time fp32->bf16 conversion of all GEMM weights into workspace.
// Layout: [head_w 3*65536 | cls_w1 3*65536 | loc_w1 3*65536 | ctr_w1 3*65536]
// ---------------------------------------------------------------------------
__global__ void wconv_k(const float* __restrict__ hw, const float* __restrict__ cw,
                        const float* __restrict__ lw, const float* __restrict__ tw,
                        unsigned short* __restrict__ o)
{
    int i = blockIdx.x * 256 + threadIdx.x;
    if (i >= 4 * 196608) return;
    int seg = i / 196608, r = i - seg * 196608;
    const float* s = (seg == 0) ? hw : (seg == 1) ? cw : (seg == 2) ? lw : tw;
    o[i] = f2bf(s[r]);
}

// ---------------------------------------------------------------------------
// Fused: dw3+BN+ReLU on x-tile and z-tile, then depthwise 5x5 xcorr.
// v4: TWO (b,c) pairs per block (grid x = B*C/2):
//   A: coalesced linear loads, no div/mod (was magic-mul per element).
//   B: 2-row x 4-col strips, 240/256 lanes (read/MAC halved vs 1-row).
//   C: both channels concurrent -> 250/256 lanes (was 125/256).
//   xt linear stride 31 (~2-way banks, free), st stride 36 (16B-aligned f4).
// ---------------------------------------------------------------------------
__global__ __launch_bounds__(256) void fused_pre_xcorr(
    const float* __restrict__ x, const float* __restrict__ z,
    const float* __restrict__ w, const float* __restrict__ g,
    const float* __restrict__ bb, const float* __restrict__ mm,
    const float* __restrict__ vv, unsigned short* __restrict__ out,
    int si_base)
{
    const int zs  = blockIdx.y;            // local stage (output buffer)
    const int si  = si_base + zs;          // global stage (inputs)
    const int bc0 = blockIdx.x * 2;        // first of 2 (b,c); same b, c even
    const int tid = threadIdx.x;

    __shared__ float xt[2 * XCST + 8];     // x tiles, linear rows (stride 31)
    __shared__ float st[2 * SCST + 16];    // dw3 features, row stride 36
    __shared__ float zt[2 * 49];
    __shared__ float ktl[2 * 25];
    __shared__ float wtl[2 * 9];
    __shared__ float sprm[4];              // inv0, beta0, inv1, beta1

    // ---- Phase A: coalesced load of both x tiles (1922 consecutive floats)
    const float* xp = x + ((size_t)si * B_ * C_ + bc0) * (XS * XS);
    #pragma unroll
    for (int k2 = 0; k2 < 8; ++k2) {
        int idx = tid + k2 * 256;
        if (idx < 2 * XS * XS) {
            int off = idx + (idx >= XS * XS ? (XCST - XS * XS) : 0);
            xt[off] = xp[idx];
        }
    }
    if (tid < 98) zt[tid] = z[((size_t)si * B_ * C_ + bc0) * 49 + tid];
    if (tid < 18) wtl[tid] = w[((size_t)si * C_ + (bc0 & (C_ - 1))) * 9 + tid];
    if (tid < 2) {
        int cg = si * C_ + (bc0 & (C_ - 1)) + tid;
        float iv = g[cg] * rsqrtf(vv[cg] + EPSF);
        sprm[tid * 2]     = iv;
        sprm[tid * 2 + 1] = bb[cg] - mm[cg] * iv;
    }
    __syncthreads();

    // ---- kernel features (two 5x5 tiles), threads 0..49
    if (tid < 50) {
        int ch = (tid >= 25) ? 1 : 0;
        int l  = tid - ch * 25;
        int oy = l / 5, ox = l - (l / 5) * 5;
        const float* zb = &zt[ch * 49];
        const float* wb = &wtl[ch * 9];
        float a = 0.f;
        #pragma unroll
        for (int dy = 0; dy < 3; ++dy)
            #pragma unroll
            for (int dx = 0; dx < 3; ++dx)
                a += zb[(oy + dy) * ZS + ox + dx] * wb[dy * 3 + dx];
        ktl[ch * 25 + l] = fmaxf(a * sprm[ch * 2] + sprm[ch * 2 + 1], 0.f);
    }

    // ---- Phase B: search features, 2-row x 4-col strips, threads 0..239
    if (tid < 240) {
        int ch    = (tid >= 120) ? 1 : 0;
        int rem   = tid - ch * 120;
        int strip = rem >> 3;              // 0..14  (rows 2s, 2s+1)
        int cgp   = rem & 7;               // 0..7   (cols 4cg..4cg+3)
        int r0    = strip * 2;
        const float* base = &xt[ch * XCST + r0 * XS + cgp * 4];
        const float* wb   = &wtl[ch * 9];
        float w0 = wb[0], w1 = wb[1], w2 = wb[2],
              w3 = wb[3], w4 = wb[4], w5 = wb[5],
              w6 = wb[6], w7 = wb[7], w8 = wb[8];
        const float inv  = sprm[ch * 2];
        const float beta = sprm[ch * 2 + 1];

        float a0 = 0.f, a1 = 0.f, a2 = 0.f, a3 = 0.f;   // row r0
        float b0 = 0.f, b1 = 0.f, b2 = 0.f, b3 = 0.f;   // row r0+1
        #pragma unroll
        for (int dy = 0; dy < 4; ++dy) {
            const float* rp = base + dy * XS;
            float v0 = rp[0], v1 = rp[1], v2 = rp[2],
                  v3 = rp[3], v4 = rp[4], v5 = rp[5];
            if (dy < 3) {
                float u0 = (dy == 0) ? w0 : (dy == 1) ? w3 : w6;
                float u1 = (dy == 0) ? w1 : (dy == 1) ? w4 : w7;
                float u2 = (dy == 0) ? w2 : (dy == 1) ? w5 : w8;
                a0 += v0 * u0 + v1 * u1 + v2 * u2;
                a1 += v1 * u0 + v2 * u1 + v3 * u2;
                a2 += v2 * u0 + v3 * u1 + v4 * u2;
                a3 += v3 * u0 + v4 * u1 + v5 * u2;
            }
            if (dy >= 1) {
                float u0 = (dy == 1) ? w0 : (dy == 2) ? w3 : w6;
                float u1 = (dy == 1) ? w1 : (dy == 2) ? w4 : w7;
                float u2 = (dy == 1) ? w2 : (dy == 2) ? w5 : w8;
                b0 += v0 * u0 + v1 * u1 + v2 * u2;
                b1 += v1 * u0 + v2 * u1 + v3 * u2;
                b2 += v2 * u0 + v3 * u1 + v4 * u2;
                b3 += v3 * u0 + v4 * u1 + v5 * u2;
            }
        }
        float4 ra;
        ra.x = fmaxf(a0 * inv + beta, 0.f);
        ra.y = fmaxf(a1 * inv + beta, 0.f);
        ra.z = fmaxf(a2 * inv + beta, 0.f);
        ra.w = fmaxf(a3 * inv + beta, 0.f);
        *(float4*)&st[ch * SCST + r0 * SRS + cgp * 4] = ra;   // cols>=29 -> pad
        if (r0 + 1 < XO) {
            float4 rb;
            rb.x = fmaxf(b0 * inv + beta, 0.f);
            rb.y = fmaxf(b1 * inv + beta, 0.f);
            rb.z = fmaxf(b2 * inv + beta, 0.f);
            rb.w = fmaxf(b3 * inv + beta, 0.f);
            *(float4*)&st[ch * SCST + (r0 + 1) * SRS + cgp * 4] = rb;
        }
    }
    __syncthreads();

    // ---- Phase C: xcorr, waves 0-1 = ch0, waves 2-3 = ch1; 125 lanes each
    {
        const int ch = tid >> 7;
        const int l  = tid & 127;
        if (l < 125) {
            const float* kb = &ktl[ch * 25];
            float kt[25];
            #pragma unroll
            for (int j = 0; j < 25; ++j) kt[j] = kb[j];
            int u  = l / 5;
            int v0 = (l - u * 5) * 5;
            const float* sbase = &st[ch * SCST + u * SRS + v0];
            float o0 = 0.f, o1 = 0.f, o2 = 0.f, o3 = 0.f, o4 = 0.f;
            #pragma unroll
            for (int p = 0; p < 5; ++p) {
                const float* rp = sbase + p * SRS;
                float r0 = rp[0], r1 = rp[1], r2 = rp[2], r3 = rp[3], r4 = rp[4],
                      r5 = rp[5], r6 = rp[6], r7 = rp[7], r8 = rp[8];
                float k0 = kt[p * 5], k1 = kt[p * 5 + 1], k2 = kt[p * 5 + 2],
                      k3 = kt[p * 5 + 3], k4 = kt[p * 5 + 4];
                o0 += r0 * k0 + r1 * k1 + r2 * k2 + r3 * k3 + r4 * k4;
                o1 += r1 * k0 + r2 * k1 + r3 * k2 + r4 * k3 + r5 * k4;
                o2 += r2 * k0 + r3 * k1 + r4 * k2 + r5 * k3 + r6 * k4;
                o3 += r3 * k0 + r4 * k1 + r5 * k2 + r6 * k3 + r7 * k4;
                o4 += r4 * k0 + r5 * k1 + r6 * k2 + r7 * k3 + r8 * k4;
            }
            unsigned short* op = out + ((size_t)zs * B_ * C_ + bc0 + ch) * OS2
                                     + u * OSP + v0;
            op[0] = f2bf(o0); op[1] = f2bf(o1); op[2] = f2bf(o2);
            op[3] = f2bf(o3); op[4] = f2bf(o4);
        }
    }
}

// ---------------------------------------------------------------------------
// Head GEMM: feat[b][o][s] = relu(bn(sum_c W[o][c] * X[b][c][s])), bf16 out.
// Block tile 128x128, K-chunks of 32, 4 waves, 16x16x32 MFMA.
// grid (5, 2, nstage*64).
// ---------------------------------------------------------------------------
__global__ __launch_bounds__(256) void c1_mfma(
    const unsigned short* __restrict__ X,
    const float* __restrict__ W,
    const unsigned short* __restrict__ Wbf,
    const float* __restrict__ g, const float* __restrict__ bb,
    const float* __restrict__ mm, const float* __restrict__ vv,
    unsigned short* __restrict__ out, int si_base)
{
    __shared__ unsigned short Abuf[4 * 128 * 8];
    __shared__ unsigned short Bbuf[4 * 128 * 8];
    __shared__ float s_inv[128], s_beta[128];

    const int tid  = threadIdx.x;
    const int wave = tid >> 6, lane = tid & 63;
    const int quad = lane >> 4, l16 = lane & 15;
    const int sb = blockIdx.x * 128;
    const int ob = blockIdx.y * 128;
    const int zs = blockIdx.z >> 6;
    const int si = si_base + zs;
    const int b  = blockIdx.z & 63;
    const int wm = (wave & 1) * 64, wn = (wave >> 1) * 64;

    const float* gs  = g  + (size_t)si * HD_;
    const float* bbs = bb + (size_t)si * HD_;
    const float* mms = mm + (size_t)si * HD_;
    const float* vvs = vv + (size_t)si * HD_;
    const float* Ws  = W  + (size_t)si * HD_ * C_;
    const unsigned short* Wbs = Wbf ? Wbf + (size_t)si * HD_ * C_ : nullptr;

    if (tid < 128) {
        int o = ob + tid;
        float iv = gs[o] * rsqrtf(vvs[o] + EPSF);
        s_inv[tid]  = iv;
        s_beta[tid] = bbs[o] - mms[o] * iv;
    }

    const int sm = tid & 127;
    const int kh = tid >> 7;
    const unsigned short* Xb = X + ((size_t)zs * B_ + b) * C_ * OS2;
    const bool npred = (sb + sm) < OS2;

    f32x4 acc[4][4];
    #pragma unroll
    for (int i = 0; i < 4; ++i)
        #pragma unroll
        for (int j = 0; j < 4; ++j)
            acc[i][j] = (f32x4){0.f, 0.f, 0.f, 0.f};

    for (int kk = 0; kk < C_; kk += 32) {
        uint4 pa0, pa1;
        if (Wbs) {
            const unsigned short* wp = Wbs + (size_t)(ob + sm) * C_ + kk + kh * 16;
            pa0 = *(const uint4*)(wp);
            pa1 = *(const uint4*)(wp + 8);
        } else {
            const float* wp = Ws + (size_t)(ob + sm) * C_ + kk + kh * 16;
            float4 w0 = *(const float4*)(wp + 0);
            float4 w1 = *(const float4*)(wp + 4);
            float4 w2 = *(const float4*)(wp + 8);
            float4 w3 = *(const float4*)(wp + 12);
            pa0.x = pk2(f2bf(w0.x), f2bf(w0.y)); pa0.y = pk2(f2bf(w0.z), f2bf(w0.w));
            pa0.z = pk2(f2bf(w1.x), f2bf(w1.y)); pa0.w = pk2(f2bf(w1.z), f2bf(w1.w));
            pa1.x = pk2(f2bf(w2.x), f2bf(w2.y)); pa1.y = pk2(f2bf(w2.z), f2bf(w2.w));
            pa1.z = pk2(f2bf(w3.x), f2bf(w3.y)); pa1.w = pk2(f2bf(w3.z), f2bf(w3.w));
        }
        *(uint4*)&Abuf[((kh * 2 + 0) * 128 + sm) * 8] = pa0;
        *(uint4*)&Abuf[((kh * 2 + 1) * 128 + sm) * 8] = pa1;

        unsigned short bu[16];
        #pragma unroll
        for (int j = 0; j < 16; ++j)
            bu[j] = npred ? Xb[(size_t)(kk + kh * 16 + j) * OS2 + sb + sm]
                          : (unsigned short)0;
        uint4 pb0, pb1;
        pb0.x = pk2(bu[0],  bu[1]);  pb0.y = pk2(bu[2],  bu[3]);
        pb0.z = pk2(bu[4],  bu[5]);  pb0.w = pk2(bu[6],  bu[7]);
        pb1.x = pk2(bu[8],  bu[9]);  pb1.y = pk2(bu[10], bu[11]);
        pb1.z = pk2(bu[12], bu[13]); pb1.w = pk2(bu[14], bu[15]);
        *(uint4*)&Bbuf[((kh * 2 + 0) * 128 + sm) * 8] = pb0;
        *(uint4*)&Bbuf[((kh * 2 + 1) * 128 + sm) * 8] = pb1;

        __syncthreads();

        s16x8 af[4], bfr[4];
        #pragma unroll
        for (int mt = 0; mt < 4; ++mt)
            af[mt] = *(const s16x8*)&Abuf[(quad * 128 + wm + mt * 16 + l16) * 8];
        #pragma unroll
        for (int nt = 0; nt < 4; ++nt)
            bfr[nt] = *(const s16x8*)&Bbuf[(quad * 128 + wn + nt * 16 + l16) * 8];
        #pragma unroll
        for (int mt = 0; mt < 4; ++mt)
            #pragma unroll
            for (int nt = 0; nt < 4; ++nt)
                acc[mt][nt] = __builtin_amdgcn_mfma_f32_16x16x32_bf16(
                    af[mt], bfr[nt], acc[mt][nt], 0, 0, 0);

        __syncthreads();
    }

    #pragma unroll
    for (int mt = 0; mt < 4; ++mt) {
        #pragma unroll
        for (int r = 0; r < 4; ++r) {
            int orow = wm + mt * 16 + quad * 4 + r;
            float iv = s_inv[orow], be = s_beta[orow];
            size_t obase = (((size_t)zs * B_ + b) * HD_ + (ob + orow)) * OS2;
            #pragma unroll
            for (int nt = 0; nt < 4; ++nt) {
                int s = sb + wn + nt * 16 + l16;
                if (s < OS2)
                    out[obase + s] = f2bf(fmaxf(acc[mt][nt][r] * iv + be, 0.f));
            }
        }
    }
}

// ---------------------------------------------------------------------------
// Fused 3-head hidden GEMM + w2 projection + softmax-weighted accumulate.
// grid (5 s-tiles, 6 o-tiles [cls,cls,loc,loc,ctr,ctr], nstage*64 b).
// ---------------------------------------------------------------------------
__global__ __launch_bounds__(256) void heads3_mfma(
    const unsigned short* __restrict__ feat,
    const float* __restrict__ w1c, const float* __restrict__ w1l, const float* __restrict__ w1t,
    const unsigned short* __restrict__ Wbf,
    const float* __restrict__ gc, const float* __restrict__ bc2, const float* __restrict__ mc, const float* __restrict__ vc,
    const float* __restrict__ gl, const float* __restrict__ bl, const float* __restrict__ ml, const float* __restrict__ vl,
    const float* __restrict__ gt, const float* __restrict__ bt, const float* __restrict__ mt2, const float* __restrict__ vt,
    const float* __restrict__ w2c, const float* __restrict__ w2l, const float* __restrict__ w2t,
    const float* __restrict__ wvc, const float* __restrict__ wvl, const float* __restrict__ wvt,
    int si_base, float* __restrict__ oacc)
{
    __shared__ unsigned short Abuf[4 * 128 * 8];
    __shared__ unsigned short Bbuf[4 * 128 * 8];
    __shared__ float s_inv[128], s_beta[128];
    __shared__ float s_w2[4 * 256];

    const int tid  = threadIdx.x;
    const int wave = tid >> 6, lane = tid & 63;
    const int quad = lane >> 4, l16 = lane & 15;
    const int sb   = blockIdx.x * 128;
    const int by   = blockIdx.y;
    const int head = by >> 1;
    const int lob  = (by & 1) * 128;
    const int zs   = blockIdx.z >> 6;
    const int si   = si_base + zs;
    const int b    = blockIdx.z & 63;
    const int wm = (wave & 1) * 64, wn = (wave >> 1) * 64;

    const float* W  = (head == 0) ? w1c : (head == 1) ? w1l : w1t;
    const float* g  = (head == 0) ? gc  : (head == 1) ? gl  : gt;
    const float* bb = (head == 0) ? bc2 : (head == 1) ? bl  : bt;
    const float* mm = (head == 0) ? mc  : (head == 1) ? ml  : mt2;
    const float* vv = (head == 0) ? vc  : (head == 1) ? vl  : vt;
    const float* w2 = (head == 0) ? w2c : (head == 1) ? w2l : w2t;
    const float* wv = (head == 0) ? wvc : (head == 1) ? wvl : wvt;
    const int  CON  = (head == 0) ? 2 : (head == 1) ? 4 : 1;

    const float* Ws  = W + (size_t)si * HD_ * C_;
    const unsigned short* Wbs =
        Wbf ? Wbf + (size_t)(head + 1) * (3 * HD_ * C_) + (size_t)si * HD_ * C_ : nullptr;
    g  += (size_t)si * HD_;  bb += (size_t)si * HD_;
    mm += (size_t)si * HD_;  vv += (size_t)si * HD_;
    w2 += (size_t)si * CON * HD_;

    if (tid < 128) {
        int o = lob + tid;
        float iv = g[o] * rsqrtf(vv[o] + EPSF);
        s_inv[tid]  = iv;
        s_beta[tid] = bb[o] - mm[o] * iv;
    }
    for (int t = tid; t < CON * 256; t += 256) s_w2[t] = w2[t];

    const int sm = tid & 127;
    const int kh = tid >> 7;
    const unsigned short* Xb = feat + ((size_t)zs * B_ + b) * C_ * OS2;
    const bool npred = (sb + sm) < OS2;

    f32x4 acc[4][4];
    #pragma unroll
    for (int i = 0; i < 4; ++i)
        #pragma unroll
        for (int j = 0; j < 4; ++j)
            acc[i][j] = (f32x4){0.f, 0.f, 0.f, 0.f};

    for (int kk = 0; kk < C_; kk += 32) {
        uint4 pa0, pa1;
        if (Wbs) {
            const unsigned short* wp = Wbs + (size_t)(lob + sm) * C_ + kk + kh * 16;
            pa0 = *(const uint4*)(wp);
            pa1 = *(const uint4*)(wp + 8);
        } else {
            const float* wp = Ws + (size_t)(lob + sm) * C_ + kk + kh * 16;
            float4 w0 = *(const float4*)(wp + 0);
            float4 w1 = *(const float4*)(wp + 4);
            float4 w2v4 = *(const float4*)(wp + 8);
            float4 w3 = *(const float4*)(wp + 12);
            pa0.x = pk2(f2bf(w0.x), f2bf(w0.y)); pa0.y = pk2(f2bf(w0.z), f2bf(w0.w));
            pa0.z = pk2(f2bf(w1.x), f2bf(w1.y)); pa0.w = pk2(f2bf(w1.z), f2bf(w1.w));
            pa1.x = pk2(f2bf(w2v4.x), f2bf(w2v4.y)); pa1.y = pk2(f2bf(w2v4.z), f2bf(w2v4.w));
            pa1.z = pk2(f2bf(w3.x), f2bf(w3.y)); pa1.w = pk2(f2bf(w3.z), f2bf(w3.w));
        }
        *(uint4*)&Abuf[((kh * 2 + 0) * 128 + sm) * 8] = pa0;
        *(uint4*)&Abuf[((kh * 2 + 1) * 128 + sm) * 8] = pa1;

        unsigned short bu[16];
        #pragma unroll
        for (int j = 0; j < 16; ++j)
            bu[j] = npred ? Xb[(size_t)(kk + kh * 16 + j) * OS2 + sb + sm]
                          : (unsigned short)0;
        uint4 pb0, pb1;
        pb0.x = pk2(bu[0],  bu[1]);  pb0.y = pk2(bu[2],  bu[3]);
        pb0.z = pk2(bu[4],  bu[5]);  pb0.w = pk2(bu[6],  bu[7]);
        pb1.x = pk2(bu[8],  bu[9]);  pb1.y = pk2(bu[10], bu[11]);
        pb1.z = pk2(bu[12], bu[13]); pb1.w = pk2(bu[14], bu[15]);
        *(uint4*)&Bbuf[((kh * 2 + 0) * 128 + sm) * 8] = pb0;
        *(uint4*)&Bbuf[((kh * 2 + 1) * 128 + sm) * 8] = pb1;

        __syncthreads();

        s16x8 af[4], bfr[4];
        #pragma unroll
        for (int mt = 0; mt < 4; ++mt)
            af[mt] = *(const s16x8*)&Abuf[(quad * 128 + wm + mt * 16 + l16) * 8];
        #pragma unroll
        for (int nt = 0; nt < 4; ++nt)
            bfr[nt] = *(const s16x8*)&Bbuf[(quad * 128 + wn + nt * 16 + l16) * 8];
        #pragma unroll
        for (int mt = 0; mt < 4; ++mt)
            #pragma unroll
            for (int nt = 0; nt < 4; ++nt)
                acc[mt][nt] = __builtin_amdgcn_mfma_f32_16x16x32_bf16(
                    af[mt], bfr[nt], acc[mt][nt], 0, 0, 0);

        __syncthreads();
    }

    // BN+ReLU in place
    #pragma unroll
    for (int mt = 0; mt < 4; ++mt)
        #pragma unroll
        for (int r = 0; r < 4; ++r) {
            int orow = wm + mt * 16 + quad * 4 + r;
            float iv = s_inv[orow], be = s_beta[orow];
            #pragma unroll
            for (int nt = 0; nt < 4; ++nt)
                acc[mt][nt][r] = fmaxf(acc[mt][nt][r] * iv + be, 0.f);
        }

    const float e0 = __expf(wv[0]), e1 = __expf(wv[1]), e2 = __expf(wv[2]);
    const float wi = ((si == 0) ? e0 : (si == 1) ? e1 : e2) / (e0 + e1 + e2);

    float* obase;
    if (head == 0)      obase = oacc + (size_t)b * 2 * OS2;
    else if (head == 1) obase = oacc + (size_t)B_ * 2 * OS2 + (size_t)b * 4 * OS2;
    else                obase = oacc + (size_t)B_ * 6 * OS2 + (size_t)b * OS2;

    for (int co = 0; co < CON; ++co) {
        float red[4] = {0.f, 0.f, 0.f, 0.f};
        #pragma unroll
        for (int mt = 0; mt < 4; ++mt)
            #pragma unroll
            for (int r = 0; r < 4; ++r) {
                float w2v = s_w2[co * 256 + lob + wm + mt * 16 + quad * 4 + r];
                #pragma unroll
                for (int nt = 0; nt < 4; ++nt)
                    red[nt] += w2v * acc[mt][nt][r];
            }
        #pragma unroll
        for (int nt = 0; nt < 4; ++nt) {
            red[nt] += __shfl_xor(red[nt], 16);
            red[nt] += __shfl_xor(red[nt], 32);
        }
        if (quad == 0) {
            #pragma unroll
            for (int nt = 0; nt < 4; ++nt) {
                int s = sb + wn + nt * 16 + l16;
                if (s < OS2)
                    atomicAdd(obase + (size_t)co * OS2 + s, wi * red[nt]);
            }
        }
    }
}

// ---------------------------------------------------------------------------
// Final bias add: out += sum_i softmax(w)[i] * b2[i][co], in place on d_out.
// ---------------------------------------------------------------------------
__global__ void bias_out(float* __restrict__ out,
    const float* __restrict__ cb2, const float* __restrict__ lb2,
    const float* __restrict__ tb2, const float* __restrict__ wvc,
    const float* __restrict__ wvl, const float* __restrict__ wvt)
{
    int n = blockIdx.x * 256 + threadIdx.x;
    if (n >= B_ * 7 * OS2) return;
    float bias;
    if (n < B_ * 2 * OS2) {
        float e0 = __expf(wvc[0]), e1 = __expf(wvc[1]), e2 = __expf(wvc[2]);
        int co = (n / OS2) & 1;
        bias = (e0 * cb2[co] + e1 * cb2[2 + co] + e2 * cb2[4 + co]) / (e0 + e1 + e2);
    } else if (n < B_ * 6 * OS2) {
        float e0 = __expf(wvl[0]), e1 = __expf(wvl[1]), e2 = __expf(wvl[2]);
        int co = ((n - B_ * 2 * OS2) / OS2) & 3;
        bias = (e0 * lb2[co] + e1 * lb2[4 + co] + e2 * lb2[8 + co]) / (e0 + e1 + e2);
    } else {
        float e0 = __expf(wvt[0]), e1 = __expf(wvt[1]), e2 = __expf(wvt[2]);
        bias = (e0 * tb2[0] + e1 * tb2[1] + e2 * tb2[2]) / (e0 + e1 + e2);
    }
    out[n] += bias;
}

__global__ void fillf_k(float* __restrict__ out, int n, float v)
{
    int i = blockIdx.x * 256 + threadIdx.x;
    if (i < n) out[i] = v;
}

// ===========================================================================
extern "C" void kernel_launch(void* const* d_in, const int* in_sizes, int n_in,
                              void* d_out, int out_size, void* d_ws, size_t ws_size,
                              hipStream_t stream)
{
    static const int EXP_SIZES[36] = {
        2408448, 47235072, 6912,
        768, 768, 768, 768,
        196608, 768, 768, 768, 768,
        196608, 768, 768, 768, 768, 1536, 6,
        196608, 768, 768, 768, 768, 3072, 12,
        196608, 768, 768, 768, 768, 768, 3,
        3, 3, 3
    };
    int bad = -1;
    if (n_in != 36) bad = 99;
    else {
        for (int i = 0; i < 36; ++i)
            if (in_sizes[i] != EXP_SIZES[i]) { bad = i; break; }
    }
    if (bad < 0 && ws_size < (size_t)40960000) bad = 90;
    if (bad < 0 && out_size != 280000) bad = 95;
    if (bad >= 0) {
        fillf_k<<<(out_size + 255) / 256, 256, 0, stream>>>(
            (float*)d_out, out_size, 500.f + 4.f * bad);
        return;
    }

    const float* z_fs   = (const float*)d_in[0];
    const float* x_fs   = (const float*)d_in[1];
    const float* pre_w  = (const float*)d_in[2];
    const float* pre_g  = (const float*)d_in[3];
    const float* pre_b  = (const float*)d_in[4];
    const float* pre_m  = (const float*)d_in[5];
    const float* pre_v  = (const float*)d_in[6];
    const float* head_w = (const float*)d_in[7];
    const float* head_g = (const float*)d_in[8];
    const float* head_b = (const float*)d_in[9];
    const float* head_m = (const float*)d_in[10];
    const float* head_v = (const float*)d_in[11];
    const float* cls_w1 = (const float*)d_in[12];
    const float* cls_g  = (const float*)d_in[13];
    const float* cls_b  = (const float*)d_in[14];
    const float* cls_m  = (const float*)d_in[15];
    const float* cls_v  = (const float*)d_in[16];
    const float* cls_w2 = (const float*)d_in[17];
    const float* cls_b2 = (const float*)d_in[18];
    const float* loc_w1 = (const float*)d_in[19];
    const float* loc_g  = (const float*)d_in[20];
    const float* loc_b  = (const float*)d_in[21];
    const float* loc_m  = (const float*)d_in[22];
    const float* loc_v  = (const float*)d_in[23];
    const float* loc_w2 = (const float*)d_in[24];
    const float* loc_b2 = (const float*)d_in[25];
    const float* ctr_w1 = (const float*)d_in[26];
    const float* ctr_g  = (const float*)d_in[27];
    const float* ctr_b  = (const float*)d_in[28];
    const float* ctr_m  = (const float*)d_in[29];
    const float* ctr_v  = (const float*)d_in[30];
    const float* ctr_w2 = (const float*)d_in[31];
    const float* ctr_b2 = (const float*)d_in[32];
    const float* w_cls  = (const float*)d_in[33];
    const float* w_loc  = (const float*)d_in[34];
    const float* w_ctr  = (const float*)d_in[35];

    const int OUT_N = B_ * 7 * OS2;           // 280,000
    const size_t stageEl = (size_t)B_ * C_ * OS2;   // 10,240,000 elems (bf16)
    // batched layout: xc[3] | feat[3] | wbf (4*3*65536 bf16)
    const size_t WBF_EL = (size_t)4 * 3 * HD_ * C_; // 786,432
    const bool batched = ws_size >= (6 * stageEl + WBF_EL) * sizeof(unsigned short);

    hipMemsetAsync(d_out, 0, (size_t)OUT_N * sizeof(float), stream);

    if (batched) {
        unsigned short* xc   = (unsigned short*)d_ws;
        unsigned short* feat = xc + 3 * stageEl;
        unsigned short* wbf  = feat + 3 * stageEl;

        wconv_k<<<(4 * 196608 + 255) / 256, 256, 0, stream>>>(
            head_w, cls_w1, loc_w1, ctr_w1, wbf);

        fused_pre_xcorr<<<dim3(B_ * C_ / 2, 3), 256, 0, stream>>>(
            x_fs, z_fs, pre_w, pre_g, pre_b, pre_m, pre_v, xc, 0);

        c1_mfma<<<dim3(5, 2, 3 * B_), 256, 0, stream>>>(
            xc, head_w, wbf, head_g, head_b, head_m, head_v, feat, 0);

        heads3_mfma<<<dim3(5, 6, 3 * B_), 256, 0, stream>>>(
            feat, cls_w1, loc_w1, ctr_w1, wbf,
            cls_g, cls_b, cls_m, cls_v,
            loc_g, loc_b, loc_m, loc_v,
            ctr_g, ctr_b, ctr_m, ctr_v,
            cls_w2, loc_w2, ctr_w2,
            w_cls, w_loc, w_ctr, 0, (float*)d_out);
    } else {
        // sequential fallback: fits exactly in 40.96 MB, converts W in-kernel
        unsigned short* xc   = (unsigned short*)d_ws;
        unsigned short* feat = xc + stageEl;

        for (int i = 0; i < 3; ++i) {
            fused_pre_xcorr<<<dim3(B_ * C_ / 2, 1), 256, 0, stream>>>(
                x_fs, z_fs, pre_w, pre_g, pre_b, pre_m, pre_v, xc, i);

            c1_mfma<<<dim3(5, 2, B_), 256, 0, stream>>>(
                xc, head_w, nullptr, head_g, head_b, head_m, head_v, feat, i);

            heads3_mfma<<<dim3(5, 6, B_), 256, 0, stream>>>(
                feat, cls_w1, loc_w1, ctr_w1, nullptr,
                cls_g, cls_b, cls_m, cls_v,
                loc_g, loc_b, loc_m, loc_v,
                ctr_g, ctr_b, ctr_m, ctr_v,
                cls_w2, loc_w2, ctr_w2,
                w_cls, w_loc, w_ctr, i, (float*)d_out);
        }
    }

    bias_out<<<(OUT_N + 255) / 256, 256, 0, stream>>>(
        (float*)d_out, cls_b2, loc_b2, ctr_b2, w_cls, w_loc, w_ctr);
}